// Round 1
// baseline (10472.928 us; speedup 1.0000x reference)
//
#include <hip/hip_runtime.h>
#include <hip/hip_bf16.h>
#include <cstddef>

// Problem constants
#define Bb 4
#define Tt 1024
#define Dd 1024
#define Hh 16
#define DH 64

// ---------------------------------------------------------------------------
// Tiled fp32 GEMM + bias: C[M,N] = A[M,K] @ W[K,N] + bias[N]
// 64x64 tile, BK=16, 256 threads, 4x4 microtile per thread.
// ---------------------------------------------------------------------------
#define TILE 64
#define BK 16

__global__ __launch_bounds__(256) void gemm_bias(const float* __restrict__ A,
                                                 const float* __restrict__ W,
                                                 const float* __restrict__ bias,
                                                 float* __restrict__ C,
                                                 int M, int N, int K) {
    __shared__ float As[BK][TILE + 4];  // [k][m], pad 4 keeps float4 alignment
    __shared__ float Bs[BK][TILE + 4];  // [k][n]

    const int tx = threadIdx.x & 15;   // 0..15 -> col group
    const int ty = threadIdx.x >> 4;   // 0..15 -> row group
    const size_t row0 = (size_t)blockIdx.y * TILE;
    const size_t col0 = (size_t)blockIdx.x * TILE;

    float acc[4][4] = {};

    for (int k0 = 0; k0 < K; k0 += BK) {
        // Load A tile (64 x 16): consecutive threads read consecutive k -> coalesced.
        for (int i = threadIdx.x; i < TILE * BK; i += 256) {
            int m = i >> 4;          // /16
            int kk = i & 15;
            As[kk][m] = A[(row0 + m) * K + k0 + kk];
        }
        // Load B tile (16 x 64): consecutive threads read consecutive n -> coalesced.
        for (int i = threadIdx.x; i < TILE * BK; i += 256) {
            int kk = i >> 6;         // /64
            int n = i & 63;
            Bs[kk][n] = W[(size_t)(k0 + kk) * N + col0 + n];
        }
        __syncthreads();

        #pragma unroll
        for (int kk = 0; kk < BK; kk++) {
            float a[4], b[4];
            const float4 a4 = *(const float4*)&As[kk][ty * 4];
            const float4 b4 = *(const float4*)&Bs[kk][tx * 4];
            a[0] = a4.x; a[1] = a4.y; a[2] = a4.z; a[3] = a4.w;
            b[0] = b4.x; b[1] = b4.y; b[2] = b4.z; b[3] = b4.w;
            #pragma unroll
            for (int i = 0; i < 4; i++)
                #pragma unroll
                for (int j = 0; j < 4; j++)
                    acc[i][j] += a[i] * b[j];
        }
        __syncthreads();
    }

    #pragma unroll
    for (int i = 0; i < 4; i++) {
        float4 o;
        float bj0 = bias[col0 + tx * 4 + 0];
        float bj1 = bias[col0 + tx * 4 + 1];
        float bj2 = bias[col0 + tx * 4 + 2];
        float bj3 = bias[col0 + tx * 4 + 3];
        o.x = acc[i][0] + bj0;
        o.y = acc[i][1] + bj1;
        o.z = acc[i][2] + bj2;
        o.w = acc[i][3] + bj3;
        *(float4*)&C[(row0 + ty * 4 + i) * N + col0 + tx * 4] = o;
    }
}

// ---------------------------------------------------------------------------
// Flash-style causal attention, fp32.
// qkv: [B, T, 3D] with q = cols [0,1024), k = [1024,2048), v = [2048,3072).
// Head h uses the 64-column slice h*64 within each section.
// out: [B, T, D] (already in the transpose(0,2,1,3).reshape layout).
// Grid: (q_tiles=16, H=16, B=4), block = 256.
// Thread t: row r = t/4 of the 64-row Q tile, column group cg = t%4 (16 cols).
// ---------------------------------------------------------------------------
#define QT 64
#define LPAD 68   // 64 + 4: float4-aligned rows, conflict-benign

__global__ __launch_bounds__(256) void attn_flash(const float* __restrict__ qkv,
                                                  const int* __restrict__ mask,
                                                  float* __restrict__ out) {
    const int qt = blockIdx.x;
    const int h  = blockIdx.y;
    const int b  = blockIdx.z;

    __shared__ float Qs[QT][LPAD];
    __shared__ float Ks[QT][LPAD];  // aliased as P after S is computed
    __shared__ float Vs[QT][LPAD];

    const int t  = threadIdx.x;
    const int r  = t >> 2;        // 0..63
    const int cg = t & 3;         // 0..3
    const int c0 = cg * 16;
    const float scale = 0.125f;   // 1/sqrt(64)

    const size_t rowQ = ((size_t)b * Tt + qt * QT + r) * (3 * Dd) + h * DH;

    // Load Q tile: thread loads 16 contiguous floats of its row.
    #pragma unroll
    for (int i = 0; i < 16; i += 4)
        *(float4*)&Qs[r][c0 + i] = *(const float4*)&qkv[rowQ + c0 + i];

    float m_old = -1e30f;
    float l = 0.0f;
    float Oacc[16] = {};

    const int qglob = qt * QT + r;

    for (int kt = 0; kt <= qt; kt++) {
        __syncthreads();  // previous PV reads of Ks/Vs done before reload
        const size_t rowK = ((size_t)b * Tt + kt * QT + r) * (3 * Dd) + h * DH;
        #pragma unroll
        for (int i = 0; i < 16; i += 4) {
            *(float4*)&Ks[r][c0 + i] = *(const float4*)&qkv[rowK + Dd + c0 + i];
            *(float4*)&Vs[r][c0 + i] = *(const float4*)&qkv[rowK + 2 * Dd + c0 + i];
        }
        __syncthreads();

        // S[r][c0+j] = scale * dot(Q[r], K[c0+j]) with causal + key mask
        float s[16];
        #pragma unroll
        for (int j = 0; j < 16; j++) {
            const int c = c0 + j;
            float acc = 0.0f;
            #pragma unroll
            for (int d = 0; d < 64; d += 4) {
                const float4 q4 = *(const float4*)&Qs[r][d];
                const float4 k4 = *(const float4*)&Ks[c][d];
                acc += q4.x * k4.x + q4.y * k4.y + q4.z * k4.z + q4.w * k4.w;
            }
            const int kg = kt * QT + c;
            const bool keep = (kg <= qglob) && (mask[b * Tt + kg] != 0);
            s[j] = keep ? acc * scale : -1e30f;
        }

        // Row reductions across 16 regs + the 4 lanes of this row group.
        float mx = s[0];
        #pragma unroll
        for (int j = 1; j < 16; j++) mx = fmaxf(mx, s[j]);
        mx = fmaxf(mx, __shfl_xor(mx, 1));
        mx = fmaxf(mx, __shfl_xor(mx, 2));
        const float m_new = fmaxf(m_old, mx);
        const float alpha = __expf(m_old - m_new);

        float p[16];
        float lsum = 0.0f;
        #pragma unroll
        for (int j = 0; j < 16; j++) {
            p[j] = __expf(s[j] - m_new);
            lsum += p[j];
        }
        lsum += __shfl_xor(lsum, 1);
        lsum += __shfl_xor(lsum, 2);
        l = l * alpha + lsum;
        m_old = m_new;
        #pragma unroll
        for (int i = 0; i < 16; i++) Oacc[i] *= alpha;

        __syncthreads();  // everyone finished reading Ks before we overwrite with P
        #pragma unroll
        for (int j = 0; j < 16; j += 4)
            *(float4*)&Ks[r][c0 + j] = make_float4(p[j], p[j + 1], p[j + 2], p[j + 3]);
        __syncthreads();

        // O[r][c0..c0+15] += sum_c P[r][c] * V[c][c0..c0+15]
        #pragma unroll 4
        for (int c = 0; c < 64; c++) {
            const float prc = Ks[r][c];
            #pragma unroll
            for (int i = 0; i < 16; i += 4) {
                const float4 v4 = *(const float4*)&Vs[c][c0 + i];
                Oacc[i + 0] += prc * v4.x;
                Oacc[i + 1] += prc * v4.y;
                Oacc[i + 2] += prc * v4.z;
                Oacc[i + 3] += prc * v4.w;
            }
        }
    }

    const float inv_l = 1.0f / l;
    const size_t rowO = ((size_t)b * Tt + qt * QT + r) * Dd + h * DH;
    #pragma unroll
    for (int i = 0; i < 16; i += 4) {
        float4 o;
        o.x = Oacc[i + 0] * inv_l;
        o.y = Oacc[i + 1] * inv_l;
        o.z = Oacc[i + 2] * inv_l;
        o.w = Oacc[i + 3] * inv_l;
        *(float4*)&out[rowO + c0 + i] = o;
    }
}

// ---------------------------------------------------------------------------
extern "C" void kernel_launch(void* const* d_in, const int* in_sizes, int n_in,
                              void* d_out, int out_size, void* d_ws, size_t ws_size,
                              hipStream_t stream) {
    const float* x     = (const float*)d_in[0];  // [B,T,D]
    const float* Wqkv  = (const float*)d_in[1];  // [D,3D]
    const float* bqkv  = (const float*)d_in[2];  // [3D]
    const float* Wproj = (const float*)d_in[3];  // [D,D]
    const float* bproj = (const float*)d_in[4];  // [D]
    const int*   mask  = (const int*)d_in[5];    // [B,T]
    float* out = (float*)d_out;                  // [B,T,D]

    float* qkv = (float*)d_ws;                          // [B,T,3D] = 50.3 MB
    float* att = qkv + (size_t)Bb * Tt * 3 * Dd;        // [B,T,D]  = 16.8 MB

    const int M = Bb * Tt;  // 4096

    // 1) qkv = x @ Wqkv + bqkv
    {
        dim3 grid((3 * Dd) / TILE, M / TILE);  // 48 x 64
        gemm_bias<<<grid, 256, 0, stream>>>(x, Wqkv, bqkv, qkv, M, 3 * Dd, Dd);
    }
    // 2) attention
    {
        dim3 grid(Tt / QT, Hh, Bb);  // 16 x 16 x 4
        attn_flash<<<grid, 256, 0, stream>>>(qkv, mask, att);
    }
    // 3) out = att @ Wproj + bproj
    {
        dim3 grid(Dd / TILE, M / TILE);  // 16 x 64
        gemm_bias<<<grid, 256, 0, stream>>>(att, Wproj, bproj, out, M, Dd, Dd);
    }
}

// Round 2
// 241.599 us; speedup vs baseline: 43.3484x; 43.3484x over previous
//
#include <hip/hip_runtime.h>
#include <hip/hip_bf16.h>
#include <cstddef>
#include <cstdint>

#define Bb 4
#define Tt 1024
#define Dd 1024
#define Hh 16

typedef __bf16 bf16x8 __attribute__((ext_vector_type(8)));
typedef __bf16 bf16x4 __attribute__((ext_vector_type(4)));
typedef float  f32x4  __attribute__((ext_vector_type(4)));

__device__ __forceinline__ void gload16(const void* g, void* l) {
    __builtin_amdgcn_global_load_lds(
        (const __attribute__((address_space(1))) void*)g,
        (__attribute__((address_space(3))) void*)l, 16, 0, 0);
}

// ---------------------------------------------------------------------------
// fp32 -> bf16 cast, vectorized (n4 = count of float4 groups)
// ---------------------------------------------------------------------------
__global__ __launch_bounds__(256) void cast_f32_bf16(const float* __restrict__ in,
                                                     __bf16* __restrict__ out, int n4) {
    int i = blockIdx.x * 256 + threadIdx.x;
    if (i < n4) {
        float4 v = ((const float4*)in)[i];
        bf16x4 o = { (__bf16)v.x, (__bf16)v.y, (__bf16)v.z, (__bf16)v.w };
        ((bf16x4*)out)[i] = o;
    }
}

// ---------------------------------------------------------------------------
// W [K][N] fp32  ->  W^T [N][K] bf16   (64x64 LDS tile transpose)
// grid: (K/64, N/64), block 256
// ---------------------------------------------------------------------------
__global__ __launch_bounds__(256) void transpose_cast(const float* __restrict__ in,
                                                      __bf16* __restrict__ out,
                                                      int K, int N) {
    __shared__ float ld[64][65];
    const int k0 = blockIdx.x * 64;
    const int n0 = blockIdx.y * 64;
    #pragma unroll
    for (int i = 0; i < 16; i++) {
        int idx = i * 256 + threadIdx.x;
        int r = idx >> 6, c = idx & 63;
        ld[r][c] = in[(size_t)(k0 + r) * N + n0 + c];
    }
    __syncthreads();
    #pragma unroll
    for (int i = 0; i < 16; i++) {
        int idx = i * 256 + threadIdx.x;
        int r = idx >> 6, c = idx & 63;
        out[(size_t)(n0 + r) * K + k0 + c] = (__bf16)ld[c][r];
    }
}

// ---------------------------------------------------------------------------
// V slice of qkv [b][t][3072] (cols 2048 + h*64 + d)  ->  vt [b][h][d][t] bf16
// grid: (T/64, H, B), block 256
// ---------------------------------------------------------------------------
__global__ __launch_bounds__(256) void v_transpose(const __bf16* __restrict__ qkv,
                                                   __bf16* __restrict__ vt) {
    __shared__ __bf16 ld[64][65];
    const int t0 = blockIdx.x * 64;
    const int h  = blockIdx.y;
    const int b  = blockIdx.z;
    const size_t src = ((size_t)(b * Tt + t0)) * 3072 + 2048 + h * 64;
    #pragma unroll
    for (int i = 0; i < 16; i++) {
        int idx = i * 256 + threadIdx.x;
        int tr = idx >> 6, dc = idx & 63;
        ld[tr][dc] = qkv[src + (size_t)tr * 3072 + dc];
    }
    __syncthreads();
    const size_t dst = ((size_t)((b * Hh + h) * 64)) * Tt + t0;
    #pragma unroll
    for (int i = 0; i < 16; i++) {
        int idx = i * 256 + threadIdx.x;
        int dr = idx >> 6, tc = idx & 63;
        vt[dst + (size_t)dr * Tt + tc] = ld[tc][dr];
    }
}

// ---------------------------------------------------------------------------
// m97-style bf16 MFMA GEMM: C[M,N] = A[M,K] @ Bt[N,K]^T + bias
// 128x128 tile, BK=32, 4 waves (2x2), each wave 64x64 = 4x4 MFMA tiles.
// out_bf16: 1 -> store bf16, 0 -> store fp32.
// ---------------------------------------------------------------------------
__global__ __launch_bounds__(256) void gemm_bf16(const __bf16* __restrict__ A,
                                                 const __bf16* __restrict__ Bt,
                                                 const float* __restrict__ bias,
                                                 void* __restrict__ Cout,
                                                 int M, int N, int K, int out_bf16) {
    __shared__ __align__(16) __bf16 As[128 * 32];
    __shared__ __align__(16) __bf16 Bs[128 * 32];
    const int tid  = threadIdx.x;
    const int lane = tid & 63;
    const int wave = tid >> 6;
    const int wy = wave >> 1, wx = wave & 1;
    const int l15 = lane & 15, quad = lane >> 4;
    const size_t row0 = (size_t)blockIdx.y * 128;
    const size_t col0 = (size_t)blockIdx.x * 128;

    f32x4 acc[4][4] = {};

    for (int k0 = 0; k0 < K; k0 += 32) {
        #pragma unroll
        for (int i = 0; i < 2; i++) {
            int chunk = i * 256 + tid;
            int r = chunk >> 2, seg = chunk & 3;  // 4 chunks of 8 bf16 per 32-wide row
            gload16(&A[(row0 + r) * K + k0 + seg * 8], &As[chunk * 8]);
        }
        #pragma unroll
        for (int i = 0; i < 2; i++) {
            int chunk = i * 256 + tid;
            int r = chunk >> 2, seg = chunk & 3;
            gload16(&Bt[(col0 + r) * K + k0 + seg * 8], &Bs[chunk * 8]);
        }
        __syncthreads();
        bf16x8 af[4], bfr[4];
        #pragma unroll
        for (int i = 0; i < 4; i++)
            af[i] = *(const bf16x8*)&As[(wy * 64 + i * 16 + l15) * 32 + quad * 8];
        #pragma unroll
        for (int j = 0; j < 4; j++)
            bfr[j] = *(const bf16x8*)&Bs[(wx * 64 + j * 16 + l15) * 32 + quad * 8];
        #pragma unroll
        for (int i = 0; i < 4; i++)
            #pragma unroll
            for (int j = 0; j < 4; j++)
                acc[i][j] = __builtin_amdgcn_mfma_f32_16x16x32_bf16(af[i], bfr[j], acc[i][j], 0, 0, 0);
        __syncthreads();
    }

    #pragma unroll
    for (int j = 0; j < 4; j++) {
        const size_t col = col0 + wx * 64 + j * 16 + l15;
        const float bj = bias[col];
        #pragma unroll
        for (int i = 0; i < 4; i++) {
            const size_t row = row0 + wy * 64 + i * 16 + quad * 4;
            #pragma unroll
            for (int r = 0; r < 4; r++) {
                float v = acc[i][j][r] + bj;
                if (out_bf16) ((__bf16*)Cout)[(row + r) * N + col] = (__bf16)v;
                else          ((float*)Cout)[(row + r) * N + col] = v;
            }
        }
    }
}

// ---------------------------------------------------------------------------
// Flash attention, bf16 MFMA. qkv: [b][t][3072] bf16 (Q at h*64, K at 1024+h*64),
// vt: [b][h][d][t] bf16. att out: [b][t][1024] bf16.
// grid (T/64, H, B), block 256 = 4 waves; wave w owns Q rows w*16..w*16+15.
// ---------------------------------------------------------------------------
__global__ __launch_bounds__(256) void attn_mfma(const __bf16* __restrict__ qkv,
                                                 const __bf16* __restrict__ vt,
                                                 const int* __restrict__ mask,
                                                 __bf16* __restrict__ att) {
    __shared__ __align__(16) __bf16 Qs[64 * 64];       // [t][d]
    __shared__ __align__(16) __bf16 Ks[64 * 64];       // [t][d]
    __shared__ __align__(16) __bf16 Vs[64 * 64];       // [d][t]  (from vt)
    __shared__ __align__(16) __bf16 Ps[4][16 * 64];    // per-wave P strip [q][t]

    const int qt = blockIdx.x, h = blockIdx.y, b = blockIdx.z;
    const int tid  = threadIdx.x;
    const int lane = tid & 63, wave = tid >> 6;
    const int l15 = lane & 15, quad = lane >> 4;

    // stage Q tile (async; first in-loop barrier waits on it)
    const size_t qbase = ((size_t)(b * Tt + qt * 64)) * 3072 + h * 64;
    #pragma unroll
    for (int i = 0; i < 2; i++) {
        int chunk = i * 256 + tid;
        int r = chunk >> 3, seg = chunk & 7;  // 8 chunks of 8 bf16 per 64-wide row
        gload16(&qkv[qbase + (size_t)r * 3072 + seg * 8], &Qs[chunk * 8]);
    }

    f32x4 Oacc[4] = {};
    float mrow[4] = { -1e30f, -1e30f, -1e30f, -1e30f };
    float lrow[4] = {};

    const size_t kbase = ((size_t)b * Tt) * 3072 + 1024 + h * 64;
    const size_t vbase = ((size_t)((b * Hh + h) * 64)) * Tt;

    for (int kt = 0; kt <= qt; kt++) {
        __syncthreads();  // previous iter done reading Ks/Vs (and Q staged, 1st iter)
        #pragma unroll
        for (int i = 0; i < 2; i++) {
            int chunk = i * 256 + tid;
            int r = chunk >> 3, seg = chunk & 7;
            gload16(&qkv[kbase + (size_t)(kt * 64 + r) * 3072 + seg * 8], &Ks[chunk * 8]);
            gload16(&vt[vbase + (size_t)r * Tt + kt * 64 + seg * 8], &Vs[chunk * 8]);
        }
        __syncthreads();

        // S strip = Q[wave rows] @ K^T : 4 col-tiles x (2 MFMAs over k=64)
        float s[4][4];  // [jtile][reg]
        #pragma unroll
        for (int j = 0; j < 4; j++) {
            f32x4 sa = {};
            #pragma unroll
            for (int kc = 0; kc < 2; kc++) {
                bf16x8 aq = *(const bf16x8*)&Qs[(wave * 16 + l15) * 64 + kc * 32 + quad * 8];
                bf16x8 bk = *(const bf16x8*)&Ks[(j * 16 + l15) * 64 + kc * 32 + quad * 8];
                sa = __builtin_amdgcn_mfma_f32_16x16x32_bf16(aq, bk, sa, 0, 0, 0);
            }
            const int colg = kt * 64 + j * 16 + l15;
            const int mv = mask[b * Tt + colg];
            #pragma unroll
            for (int r = 0; r < 4; r++) {
                bool keep = (mv != 0);
                if (kt == qt) keep = keep && (j * 16 + l15 <= wave * 16 + quad * 4 + r);
                s[j][r] = keep ? sa[r] * 0.125f : -1e30f;
            }
        }

        // online softmax per row (lane holds rows quad*4+r, cols j*16+l15)
        #pragma unroll
        for (int r = 0; r < 4; r++) {
            float mx = fmaxf(fmaxf(s[0][r], s[1][r]), fmaxf(s[2][r], s[3][r]));
            mx = fmaxf(mx, __shfl_xor(mx, 1));
            mx = fmaxf(mx, __shfl_xor(mx, 2));
            mx = fmaxf(mx, __shfl_xor(mx, 4));
            mx = fmaxf(mx, __shfl_xor(mx, 8));
            const float mnew = fmaxf(mrow[r], mx);
            const float alpha = __expf(mrow[r] - mnew);
            float p[4], ls = 0.f;
            #pragma unroll
            for (int j = 0; j < 4; j++) { p[j] = __expf(s[j][r] - mnew); ls += p[j]; }
            #pragma unroll
            for (int j = 0; j < 4; j++)
                Ps[wave][(quad * 4 + r) * 64 + j * 16 + l15] = (__bf16)p[j];
            ls += __shfl_xor(ls, 1);
            ls += __shfl_xor(ls, 2);
            ls += __shfl_xor(ls, 4);
            ls += __shfl_xor(ls, 8);
            lrow[r] = lrow[r] * alpha + ls;
            mrow[r] = mnew;
            #pragma unroll
            for (int n = 0; n < 4; n++) Oacc[n][r] *= alpha;
        }

        // O strip += P @ V : P from per-wave LDS (A-layout), V from Vs[d][t] (B-layout)
        #pragma unroll
        for (int n = 0; n < 4; n++) {
            #pragma unroll
            for (int kc = 0; kc < 2; kc++) {
                bf16x8 ap = *(const bf16x8*)&Ps[wave][l15 * 64 + kc * 32 + quad * 8];
                bf16x8 bv = *(const bf16x8*)&Vs[(n * 16 + l15) * 64 + kc * 32 + quad * 8];
                Oacc[n] = __builtin_amdgcn_mfma_f32_16x16x32_bf16(ap, bv, Oacc[n], 0, 0, 0);
            }
        }
    }

    // epilogue: normalize and store bf16 (att feeds the proj GEMM)
    const size_t obase = ((size_t)(b * Tt + qt * 64 + wave * 16 + quad * 4)) * Dd + h * 64;
    #pragma unroll
    for (int r = 0; r < 4; r++) {
        const float inv = 1.0f / lrow[r];
        #pragma unroll
        for (int n = 0; n < 4; n++)
            att[obase + (size_t)r * Dd + n * 16 + l15] = (__bf16)(Oacc[n][r] * inv);
    }
}

// ---------------------------------------------------------------------------
extern "C" void kernel_launch(void* const* d_in, const int* in_sizes, int n_in,
                              void* d_out, int out_size, void* d_ws, size_t ws_size,
                              hipStream_t stream) {
    const float* x     = (const float*)d_in[0];  // [B,T,D]
    const float* Wqkv  = (const float*)d_in[1];  // [D,3D]
    const float* bqkv  = (const float*)d_in[2];  // [3D]
    const float* Wproj = (const float*)d_in[3];  // [D,D]
    const float* bproj = (const float*)d_in[4];  // [D]
    const int*   mask  = (const int*)d_in[5];    // [B,T]
    float* out = (float*)d_out;                  // [B,T,D] fp32

    __bf16* xb  = (__bf16*)d_ws;                         // 4096*1024
    __bf16* wqT = xb  + (size_t)4096 * 1024;             // 3072*1024
    __bf16* wpT = wqT + (size_t)3072 * 1024;             // 1024*1024
    __bf16* qkv = wpT + (size_t)1024 * 1024;             // 4096*3072
    __bf16* vt  = qkv + (size_t)4096 * 3072;             // 4*16*64*1024
    __bf16* att = vt  + (size_t)4 * 16 * 64 * 1024;      // 4096*1024
    // total 28M bf16 = 56 MB

    cast_f32_bf16<<<4096, 256, 0, stream>>>(x, xb, (4096 * 1024) / 4);
    transpose_cast<<<dim3(16, 48), 256, 0, stream>>>(Wqkv, wqT, 1024, 3072);
    transpose_cast<<<dim3(16, 16), 256, 0, stream>>>(Wproj, wpT, 1024, 1024);

    gemm_bf16<<<dim3(24, 32), 256, 0, stream>>>(xb, wqT, bqkv, qkv, 4096, 3072, 1024, 1);

    v_transpose<<<dim3(16, 16, 4), 256, 0, stream>>>(qkv, vt);
    attn_mfma<<<dim3(16, 16, 4), 256, 0, stream>>>(qkv, vt, mask, att);

    gemm_bf16<<<dim3(8, 32), 256, 0, stream>>>(att, wpT, bproj, out, 4096, 1024, 1024, 0);
}

// Round 3
// 186.720 us; speedup vs baseline: 56.0891x; 1.2939x over previous
//
#include <hip/hip_runtime.h>
#include <hip/hip_bf16.h>
#include <cstddef>
#include <cstdint>

#define Bb 4
#define Tt 1024
#define Dd 1024
#define Hh 16

typedef __bf16 bf16x8 __attribute__((ext_vector_type(8)));
typedef __bf16 bf16x4 __attribute__((ext_vector_type(4)));
typedef float  f32x4  __attribute__((ext_vector_type(4)));

__device__ __forceinline__ void gload16(const void* g, void* l) {
    __builtin_amdgcn_global_load_lds(
        (const __attribute__((address_space(1))) void*)g,
        (__attribute__((address_space(3))) void*)l, 16, 0, 0);
}

// ---------------------------------------------------------------------------
// fp32 -> bf16 cast
// ---------------------------------------------------------------------------
__global__ __launch_bounds__(256) void cast_f32_bf16(const float* __restrict__ in,
                                                     __bf16* __restrict__ out, int n4) {
    int i = blockIdx.x * 256 + threadIdx.x;
    if (i < n4) {
        float4 v = ((const float4*)in)[i];
        bf16x4 o = { (__bf16)v.x, (__bf16)v.y, (__bf16)v.z, (__bf16)v.w };
        ((bf16x4*)out)[i] = o;
    }
}

// ---------------------------------------------------------------------------
// W [K][N] fp32 -> W^T [N][K] bf16
// ---------------------------------------------------------------------------
__global__ __launch_bounds__(256) void transpose_cast(const float* __restrict__ in,
                                                      __bf16* __restrict__ out,
                                                      int K, int N) {
    __shared__ float ld[64][65];
    const int k0 = blockIdx.x * 64;
    const int n0 = blockIdx.y * 64;
    #pragma unroll
    for (int i = 0; i < 16; i++) {
        int idx = i * 256 + threadIdx.x;
        int r = idx >> 6, c = idx & 63;
        ld[r][c] = in[(size_t)(k0 + r) * N + n0 + c];
    }
    __syncthreads();
    #pragma unroll
    for (int i = 0; i < 16; i++) {
        int idx = i * 256 + threadIdx.x;
        int r = idx >> 6, c = idx & 63;
        out[(size_t)(n0 + r) * K + k0 + c] = (__bf16)ld[c][r];
    }
}

// ---------------------------------------------------------------------------
// 128x128 MFMA GEMM: C = A[M,K] @ Bt[N,K]^T + bias
// mode 0: fp32 out.  mode 1 (qkv): bf16 out, cols<1024 scaled by 0.125 (fold
// 1/sqrt(DH) into Q), cols>=2048 also scattered to vt[b][h][d][t].
// ---------------------------------------------------------------------------
__global__ __launch_bounds__(256) void gemm_bf16(const __bf16* __restrict__ A,
                                                 const __bf16* __restrict__ Bt,
                                                 const float* __restrict__ bias,
                                                 void* __restrict__ Cout,
                                                 __bf16* __restrict__ vtout,
                                                 int M, int N, int K, int mode) {
    __shared__ __align__(16) __bf16 As[128 * 32];
    __shared__ __align__(16) __bf16 Bs[128 * 32];
    const int tid  = threadIdx.x;
    const int lane = tid & 63;
    const int wave = tid >> 6;
    const int wy = wave >> 1, wx = wave & 1;
    const int l15 = lane & 15, quad = lane >> 4;
    const size_t row0 = (size_t)blockIdx.y * 128;
    const size_t col0 = (size_t)blockIdx.x * 128;

    f32x4 acc[4][4] = {};

    for (int k0 = 0; k0 < K; k0 += 32) {
        #pragma unroll
        for (int i = 0; i < 2; i++) {
            int chunk = i * 256 + tid;
            int r = chunk >> 2, seg = chunk & 3;
            gload16(&A[(row0 + r) * K + k0 + seg * 8], &As[chunk * 8]);
        }
        #pragma unroll
        for (int i = 0; i < 2; i++) {
            int chunk = i * 256 + tid;
            int r = chunk >> 2, seg = chunk & 3;
            gload16(&Bt[(col0 + r) * K + k0 + seg * 8], &Bs[chunk * 8]);
        }
        __syncthreads();
        bf16x8 af[4], bfr[4];
        #pragma unroll
        for (int i = 0; i < 4; i++)
            af[i] = *(const bf16x8*)&As[(wy * 64 + i * 16 + l15) * 32 + quad * 8];
        #pragma unroll
        for (int j = 0; j < 4; j++)
            bfr[j] = *(const bf16x8*)&Bs[(wx * 64 + j * 16 + l15) * 32 + quad * 8];
        #pragma unroll
        for (int i = 0; i < 4; i++)
            #pragma unroll
            for (int j = 0; j < 4; j++)
                acc[i][j] = __builtin_amdgcn_mfma_f32_16x16x32_bf16(af[i], bfr[j], acc[i][j], 0, 0, 0);
        __syncthreads();
    }

    #pragma unroll
    for (int j = 0; j < 4; j++) {
        const size_t col = col0 + wx * 64 + j * 16 + l15;
        const float bj = bias[col];
        const float scale = (mode == 1 && col < 1024) ? 0.125f : 1.0f;
        #pragma unroll
        for (int i = 0; i < 4; i++) {
            const size_t row = row0 + wy * 64 + i * 16 + quad * 4;
            #pragma unroll
            for (int r = 0; r < 4; r++) {
                float v = (acc[i][j][r] + bj) * scale;
                if (mode == 1) {
                    __bf16 bv_ = (__bf16)v;
                    ((__bf16*)Cout)[(row + r) * N + col] = bv_;
                    if (col >= 2048) {  // scatter V to vt[b][h][d][t]
                        size_t rw = row + r;
                        int bidx = (int)(rw >> 10), t = (int)(rw & 1023);
                        int hd = (int)col - 2048;
                        vtout[((size_t)((bidx * Hh + (hd >> 6)) * 64 + (hd & 63))) * Tt + t] = bv_;
                    }
                } else {
                    ((float*)Cout)[(row + r) * N + col] = v;
                }
            }
        }
    }
}

// ---------------------------------------------------------------------------
// 128x64-tile GEMM for the proj (N=1024 -> 512 blocks, 2/CU). fp32 out.
// ---------------------------------------------------------------------------
__global__ __launch_bounds__(256) void gemm_bf16_n64(const __bf16* __restrict__ A,
                                                     const __bf16* __restrict__ Bt,
                                                     const float* __restrict__ bias,
                                                     float* __restrict__ Cout,
                                                     int M, int N, int K) {
    __shared__ __align__(16) __bf16 As[128 * 32];
    __shared__ __align__(16) __bf16 Bs[64 * 32];
    const int tid  = threadIdx.x;
    const int lane = tid & 63;
    const int wave = tid >> 6;
    const int wy = wave >> 1, wx = wave & 1;
    const int l15 = lane & 15, quad = lane >> 4;
    const size_t row0 = (size_t)blockIdx.y * 128;
    const size_t col0 = (size_t)blockIdx.x * 64;

    f32x4 acc[4][2] = {};

    for (int k0 = 0; k0 < K; k0 += 32) {
        #pragma unroll
        for (int i = 0; i < 2; i++) {
            int chunk = i * 256 + tid;
            int r = chunk >> 2, seg = chunk & 3;
            gload16(&A[(row0 + r) * K + k0 + seg * 8], &As[chunk * 8]);
        }
        {
            int chunk = tid;
            int r = chunk >> 2, seg = chunk & 3;
            gload16(&Bt[(col0 + r) * K + k0 + seg * 8], &Bs[chunk * 8]);
        }
        __syncthreads();
        bf16x8 af[4], bfr[2];
        #pragma unroll
        for (int i = 0; i < 4; i++)
            af[i] = *(const bf16x8*)&As[(wy * 64 + i * 16 + l15) * 32 + quad * 8];
        #pragma unroll
        for (int j = 0; j < 2; j++)
            bfr[j] = *(const bf16x8*)&Bs[(wx * 32 + j * 16 + l15) * 32 + quad * 8];
        #pragma unroll
        for (int i = 0; i < 4; i++)
            #pragma unroll
            for (int j = 0; j < 2; j++)
                acc[i][j] = __builtin_amdgcn_mfma_f32_16x16x32_bf16(af[i], bfr[j], acc[i][j], 0, 0, 0);
        __syncthreads();
    }

    #pragma unroll
    for (int j = 0; j < 2; j++) {
        const size_t col = col0 + wx * 32 + j * 16 + l15;
        const float bj = bias[col];
        #pragma unroll
        for (int i = 0; i < 4; i++) {
            const size_t row = row0 + wy * 64 + i * 16 + quad * 4;
            #pragma unroll
            for (int r = 0; r < 4; r++)
                Cout[(row + r) * N + col] = acc[i][j][r] + bj;
        }
    }
}

// ---------------------------------------------------------------------------
// Flash attention, bf16 MFMA, folded-pair Q tiles for load balance.
// Block p handles Q-tiles qlo=p and qhi=15-p (17 strip-iters each block).
// Qs rows interleaved: wave w rows [w*32, w*32+16) = qlo strip, [+16,+32) = qhi.
// XOR chunk swizzle (chunk ^ row&7) on all tiles (applied at DMA source side)
// -> conflict-free ds_read_b128 frags. No online max (scores bounded; scale
// pre-folded into Q by gemm mode 1). l computed via ones-B MFMA.
// ---------------------------------------------------------------------------
__global__ __launch_bounds__(256, 2) void attn_mfma(const __bf16* __restrict__ qkv,
                                                    const __bf16* __restrict__ vt,
                                                    const int* __restrict__ mask,
                                                    __bf16* __restrict__ att) {
    __shared__ __align__(16) __bf16 Qs[128 * 64];
    __shared__ __align__(16) __bf16 Ks[2][64 * 64];
    __shared__ __align__(16) __bf16 Vs[2][64 * 64];
    __shared__ __align__(16) __bf16 Ps[4][16 * 64];

    const int p = blockIdx.x, h = blockIdx.y, b = blockIdx.z;
    const int qlo = p, qhi = 15 - p, nk = 16 - p;
    const int tid = threadIdx.x, lane = tid & 63, wave = tid >> 6;
    const int l15 = lane & 15, quad = lane >> 4;

    // stage Q (swizzled source, strip-interleaved rows)
    #pragma unroll
    for (int i = 0; i < 4; i++) {
        int c = i * 256 + tid;
        int rr = c >> 3, ch = c & 7;
        int w_ = rr >> 5, s_ = (rr >> 4) & 1, r16 = rr & 15;
        int grow = (s_ ? qhi : qlo) * 64 + w_ * 16 + r16;
        gload16(&qkv[((size_t)(b * Tt + grow)) * 3072 + h * 64 + ((ch ^ (rr & 7)) * 8)],
                &Qs[c * 8]);
    }
    // stage K/V for kt=0 into buf 0
    #pragma unroll
    for (int i = 0; i < 2; i++) {
        int c = i * 256 + tid;
        int rr = c >> 3, ch = c & 7, sw = (ch ^ (rr & 7)) * 8;
        gload16(&qkv[((size_t)(b * Tt + rr)) * 3072 + 1024 + h * 64 + sw], &Ks[0][c * 8]);
        gload16(&vt[((size_t)((b * Hh + h) * 64 + rr)) * Tt + sw], &Vs[0][c * 8]);
    }

    f32x4 Oacc[2][4] = {};
    f32x4 lacc[2] = {};
    bf16x8 ones;
    #pragma unroll
    for (int i = 0; i < 8; i++) ones[i] = (__bf16)1.0f;

    for (int kt = 0; kt < nk; kt++) {
        __syncthreads();  // staged buf[kt&1] visible; prev reads of buf[kt&1^1] done
        const int cur = kt & 1;
        if (kt + 1 < nk) {  // prefetch next K/V, in flight through this whole iter
            #pragma unroll
            for (int i = 0; i < 2; i++) {
                int c = i * 256 + tid;
                int rr = c >> 3, ch = c & 7, sw = (ch ^ (rr & 7)) * 8;
                gload16(&qkv[((size_t)(b * Tt + (kt + 1) * 64 + rr)) * 3072 + 1024 + h * 64 + sw],
                        &Ks[cur ^ 1][c * 8]);
                gload16(&vt[((size_t)((b * Hh + h) * 64 + rr)) * Tt + (kt + 1) * 64 + sw],
                        &Vs[cur ^ 1][c * 8]);
            }
        }
        int mv[4];
        #pragma unroll
        for (int j = 0; j < 4; j++) mv[j] = mask[b * Tt + kt * 64 + j * 16 + l15];

        // K/V fragments loaded once, shared by both strips
        bf16x8 bk[4][2], bv[4][2];
        #pragma unroll
        for (int j = 0; j < 4; j++)
            #pragma unroll
            for (int kc = 0; kc < 2; kc++) {
                int sw = ((kc * 4 + quad) ^ (l15 & 7)) * 8;
                bk[j][kc] = *(const bf16x8*)&Ks[cur][(j * 16 + l15) * 64 + sw];
                bv[j][kc] = *(const bf16x8*)&Vs[cur][(j * 16 + l15) * 64 + sw];
            }

        #pragma unroll
        for (int s = 1; s >= 0; s--) {
            if (s == 0 && kt > qlo) continue;  // wave-uniform skip
            const int tile = s ? qhi : qlo;
            const int rowbase = wave * 32 + s * 16;
            bf16x8 aq0 = *(const bf16x8*)&Qs[(rowbase + l15) * 64 + ((quad ^ (l15 & 7)) * 8)];
            bf16x8 aq1 = *(const bf16x8*)&Qs[(rowbase + l15) * 64 + (((4 + quad) ^ (l15 & 7)) * 8)];
            #pragma unroll
            for (int j = 0; j < 4; j++) {
                f32x4 sa = {};
                sa = __builtin_amdgcn_mfma_f32_16x16x32_bf16(aq0, bk[j][0], sa, 0, 0, 0);
                sa = __builtin_amdgcn_mfma_f32_16x16x32_bf16(aq1, bk[j][1], sa, 0, 0, 0);
                #pragma unroll
                for (int r = 0; r < 4; r++) {
                    bool keep = (mv[j] != 0);
                    if (kt == tile) keep = keep && (j * 16 + l15 <= wave * 16 + quad * 4 + r);
                    float pe = keep ? __expf(sa[r]) : 0.0f;  // scale folded into Q
                    int row = quad * 4 + r;
                    int chs = ((j * 2 + (l15 >> 3)) ^ (row & 7)) * 8 + (l15 & 7);
                    Ps[wave][row * 64 + chs] = (__bf16)pe;
                }
            }
            bf16x8 ap0 = *(const bf16x8*)&Ps[wave][l15 * 64 + ((quad ^ (l15 & 7)) * 8)];
            bf16x8 ap1 = *(const bf16x8*)&Ps[wave][l15 * 64 + (((4 + quad) ^ (l15 & 7)) * 8)];
            #pragma unroll
            for (int n = 0; n < 4; n++) {
                Oacc[s][n] = __builtin_amdgcn_mfma_f32_16x16x32_bf16(ap0, bv[n][0], Oacc[s][n], 0, 0, 0);
                Oacc[s][n] = __builtin_amdgcn_mfma_f32_16x16x32_bf16(ap1, bv[n][1], Oacc[s][n], 0, 0, 0);
            }
            lacc[s] = __builtin_amdgcn_mfma_f32_16x16x32_bf16(ap0, ones, lacc[s], 0, 0, 0);
            lacc[s] = __builtin_amdgcn_mfma_f32_16x16x32_bf16(ap1, ones, lacc[s], 0, 0, 0);
        }
    }

    #pragma unroll
    for (int s = 0; s < 2; s++) {
        const int tile = s ? qhi : qlo;
        #pragma unroll
        for (int r = 0; r < 4; r++) {
            const int grow = tile * 64 + wave * 16 + quad * 4 + r;
            const float inv = 1.0f / lacc[s][r];
            #pragma unroll
            for (int n = 0; n < 4; n++)
                att[((size_t)(b * Tt + grow)) * Dd + h * 64 + n * 16 + l15] =
                    (__bf16)(Oacc[s][n][r] * inv);
        }
    }
}

// ---------------------------------------------------------------------------
extern "C" void kernel_launch(void* const* d_in, const int* in_sizes, int n_in,
                              void* d_out, int out_size, void* d_ws, size_t ws_size,
                              hipStream_t stream) {
    const float* x     = (const float*)d_in[0];
    const float* Wqkv  = (const float*)d_in[1];
    const float* bqkv  = (const float*)d_in[2];
    const float* Wproj = (const float*)d_in[3];
    const float* bproj = (const float*)d_in[4];
    const int*   mask  = (const int*)d_in[5];
    float* out = (float*)d_out;

    __bf16* xb  = (__bf16*)d_ws;                         // 4096*1024
    __bf16* wqT = xb  + (size_t)4096 * 1024;             // 3072*1024
    __bf16* wpT = wqT + (size_t)3072 * 1024;             // 1024*1024
    __bf16* qkv = wpT + (size_t)1024 * 1024;             // 4096*3072
    __bf16* vt  = qkv + (size_t)4096 * 3072;             // 4*16*64*1024
    __bf16* att = vt  + (size_t)4 * 16 * 64 * 1024;      // 4096*1024

    cast_f32_bf16<<<4096, 256, 0, stream>>>(x, xb, (4096 * 1024) / 4);
    transpose_cast<<<dim3(16, 48), 256, 0, stream>>>(Wqkv, wqT, 1024, 3072);
    transpose_cast<<<dim3(16, 16), 256, 0, stream>>>(Wproj, wpT, 1024, 1024);

    // qkv = x @ Wqkv + b  (Q cols pre-scaled by 0.125; V scattered to vt)
    gemm_bf16<<<dim3(24, 32), 256, 0, stream>>>(xb, wqT, bqkv, qkv, vt, 4096, 3072, 1024, 1);

    attn_mfma<<<dim3(8, 16, 4), 256, 0, stream>>>(qkv, vt, mask, att);

    gemm_bf16_n64<<<dim3(16, 32), 256, 0, stream>>>(att, wpT, bproj, out, 4096, 1024, 1024);
}

// Round 4
// 176.207 us; speedup vs baseline: 59.4353x; 1.0597x over previous
//
#include <hip/hip_runtime.h>
#include <hip/hip_bf16.h>
#include <cstddef>
#include <cstdint>

#define Bb 4
#define Tt 1024
#define Dd 1024
#define Hh 16

typedef __bf16 bf16x8 __attribute__((ext_vector_type(8)));
typedef __bf16 bf16x4 __attribute__((ext_vector_type(4)));
typedef float  f32x4  __attribute__((ext_vector_type(4)));

__device__ __forceinline__ void gload16(const void* g, void* l) {
    __builtin_amdgcn_global_load_lds(
        (const __attribute__((address_space(1))) void*)g,
        (__attribute__((address_space(3))) void*)l, 16, 0, 0);
}

// ---------------------------------------------------------------------------
// fp32 -> bf16 cast
// ---------------------------------------------------------------------------
__global__ __launch_bounds__(256) void cast_f32_bf16(const float* __restrict__ in,
                                                     __bf16* __restrict__ out, int n4) {
    int i = blockIdx.x * 256 + threadIdx.x;
    if (i < n4) {
        float4 v = ((const float4*)in)[i];
        bf16x4 o = { (__bf16)v.x, (__bf16)v.y, (__bf16)v.z, (__bf16)v.w };
        ((bf16x4*)out)[i] = o;
    }
}

// ---------------------------------------------------------------------------
// W [K][N] fp32 -> W^T [N][K] bf16
// ---------------------------------------------------------------------------
__global__ __launch_bounds__(256) void transpose_cast(const float* __restrict__ in,
                                                      __bf16* __restrict__ out,
                                                      int K, int N) {
    __shared__ float ld[64][65];
    const int k0 = blockIdx.x * 64;
    const int n0 = blockIdx.y * 64;
    #pragma unroll
    for (int i = 0; i < 16; i++) {
        int idx = i * 256 + threadIdx.x;
        int r = idx >> 6, c = idx & 63;
        ld[r][c] = in[(size_t)(k0 + r) * N + n0 + c];
    }
    __syncthreads();
    #pragma unroll
    for (int i = 0; i < 16; i++) {
        int idx = i * 256 + threadIdx.x;
        int r = idx >> 6, c = idx & 63;
        out[(size_t)(n0 + r) * K + k0 + c] = (__bf16)ld[c][r];
    }
}

// ---------------------------------------------------------------------------
// V slice of qkv [b][t][3072] (cols 2048 + h*64 + d) -> vt [b][h][d][t] bf16
// ---------------------------------------------------------------------------
__global__ __launch_bounds__(256) void v_transpose(const __bf16* __restrict__ qkv,
                                                   __bf16* __restrict__ vt) {
    __shared__ __bf16 ld[64][65];
    const int t0 = blockIdx.x * 64;
    const int h  = blockIdx.y;
    const int b  = blockIdx.z;
    const size_t src = ((size_t)(b * Tt + t0)) * 3072 + 2048 + h * 64;
    #pragma unroll
    for (int i = 0; i < 16; i++) {
        int idx = i * 256 + threadIdx.x;
        int tr = idx >> 6, dc = idx & 63;
        ld[tr][dc] = qkv[src + (size_t)tr * 3072 + dc];
    }
    __syncthreads();
    const size_t dst = ((size_t)((b * Hh + h) * 64)) * Tt + t0;
    #pragma unroll
    for (int i = 0; i < 16; i++) {
        int idx = i * 256 + threadIdx.x;
        int dr = idx >> 6, tc = idx & 63;
        vt[dst + (size_t)dr * Tt + tc] = ld[tc][dr];
    }
}

// ---------------------------------------------------------------------------
// 128x128 MFMA GEMM, BK=64, XOR-8 swizzled LDS (conflict-free frag reads).
// C = A[M,K] @ Bt[N,K]^T + bias.
// mode 0: fp32 out. mode 1 (qkv): bf16 out, cols<1024 scaled by 0.125.
// ---------------------------------------------------------------------------
__global__ __launch_bounds__(256) void gemm_bf16(const __bf16* __restrict__ A,
                                                 const __bf16* __restrict__ Bt,
                                                 const float* __restrict__ bias,
                                                 void* __restrict__ Cout,
                                                 int M, int N, int K, int mode) {
    __shared__ __align__(16) __bf16 As[128 * 64];
    __shared__ __align__(16) __bf16 Bs[128 * 64];
    const int tid  = threadIdx.x;
    const int lane = tid & 63;
    const int wave = tid >> 6;
    const int wy = wave >> 1, wx = wave & 1;
    const int l15 = lane & 15, quad = lane >> 4;
    const size_t row0 = (size_t)blockIdx.y * 128;
    const size_t col0 = (size_t)blockIdx.x * 128;

    f32x4 acc[4][4] = {};

    for (int k0 = 0; k0 < K; k0 += 64) {
        // stage A,B: 1024 chunks of 8 bf16 each; chunk c holds source
        // (row r=c>>3, seg=(c&7)^(r&7)) -> conflict-free swizzled layout
        #pragma unroll
        for (int i = 0; i < 4; i++) {
            int c = i * 256 + tid;
            int r = c >> 3, seg = (c & 7) ^ (r & 7);
            gload16(&A[(row0 + r) * K + k0 + seg * 8], &As[c * 8]);
        }
        #pragma unroll
        for (int i = 0; i < 4; i++) {
            int c = i * 256 + tid;
            int r = c >> 3, seg = (c & 7) ^ (r & 7);
            gload16(&Bt[(col0 + r) * K + k0 + seg * 8], &Bs[c * 8]);
        }
        __syncthreads();
        #pragma unroll
        for (int kc = 0; kc < 2; kc++) {
            bf16x8 af[4], bfr[4];
            #pragma unroll
            for (int i = 0; i < 4; i++)
                af[i] = *(const bf16x8*)&As[(wy * 64 + i * 16 + l15) * 64 +
                                            (((kc * 4 + quad) ^ (l15 & 7)) * 8)];
            #pragma unroll
            for (int j = 0; j < 4; j++)
                bfr[j] = *(const bf16x8*)&Bs[(wx * 64 + j * 16 + l15) * 64 +
                                             (((kc * 4 + quad) ^ (l15 & 7)) * 8)];
            #pragma unroll
            for (int i = 0; i < 4; i++)
                #pragma unroll
                for (int j = 0; j < 4; j++)
                    acc[i][j] = __builtin_amdgcn_mfma_f32_16x16x32_bf16(af[i], bfr[j], acc[i][j], 0, 0, 0);
        }
        __syncthreads();
    }

    #pragma unroll
    for (int j = 0; j < 4; j++) {
        const size_t col = col0 + wx * 64 + j * 16 + l15;
        const float bj = bias[col];
        const float scale = (mode == 1 && col < 1024) ? 0.125f : 1.0f;
        #pragma unroll
        for (int i = 0; i < 4; i++) {
            const size_t row = row0 + wy * 64 + i * 16 + quad * 4;
            #pragma unroll
            for (int r = 0; r < 4; r++) {
                float v = (acc[i][j][r] + bj) * scale;
                if (mode == 1) ((__bf16*)Cout)[(row + r) * N + col] = (__bf16)v;
                else           ((float*)Cout)[(row + r) * N + col] = v;
            }
        }
    }
}

// ---------------------------------------------------------------------------
// 128x64-tile GEMM (proj), BK=64, swizzled. fp32 out.
// ---------------------------------------------------------------------------
__global__ __launch_bounds__(256) void gemm_bf16_n64(const __bf16* __restrict__ A,
                                                     const __bf16* __restrict__ Bt,
                                                     const float* __restrict__ bias,
                                                     float* __restrict__ Cout,
                                                     int M, int N, int K) {
    __shared__ __align__(16) __bf16 As[128 * 64];
    __shared__ __align__(16) __bf16 Bs[64 * 64];
    const int tid  = threadIdx.x;
    const int lane = tid & 63;
    const int wave = tid >> 6;
    const int wy = wave >> 1, wx = wave & 1;
    const int l15 = lane & 15, quad = lane >> 4;
    const size_t row0 = (size_t)blockIdx.y * 128;
    const size_t col0 = (size_t)blockIdx.x * 64;

    f32x4 acc[4][2] = {};

    for (int k0 = 0; k0 < K; k0 += 64) {
        #pragma unroll
        for (int i = 0; i < 4; i++) {
            int c = i * 256 + tid;
            int r = c >> 3, seg = (c & 7) ^ (r & 7);
            gload16(&A[(row0 + r) * K + k0 + seg * 8], &As[c * 8]);
        }
        #pragma unroll
        for (int i = 0; i < 2; i++) {
            int c = i * 256 + tid;
            int r = c >> 3, seg = (c & 7) ^ (r & 7);
            gload16(&Bt[(col0 + r) * K + k0 + seg * 8], &Bs[c * 8]);
        }
        __syncthreads();
        #pragma unroll
        for (int kc = 0; kc < 2; kc++) {
            bf16x8 af[4], bfr[2];
            #pragma unroll
            for (int i = 0; i < 4; i++)
                af[i] = *(const bf16x8*)&As[(wy * 64 + i * 16 + l15) * 64 +
                                            (((kc * 4 + quad) ^ (l15 & 7)) * 8)];
            #pragma unroll
            for (int j = 0; j < 2; j++)
                bfr[j] = *(const bf16x8*)&Bs[(wx * 32 + j * 16 + l15) * 64 +
                                             (((kc * 4 + quad) ^ (l15 & 7)) * 8)];
            #pragma unroll
            for (int i = 0; i < 4; i++)
                #pragma unroll
                for (int j = 0; j < 2; j++)
                    acc[i][j] = __builtin_amdgcn_mfma_f32_16x16x32_bf16(af[i], bfr[j], acc[i][j], 0, 0, 0);
        }
        __syncthreads();
    }

    #pragma unroll
    for (int j = 0; j < 2; j++) {
        const size_t col = col0 + wx * 32 + j * 16 + l15;
        const float bj = bias[col];
        #pragma unroll
        for (int i = 0; i < 4; i++) {
            const size_t row = row0 + wy * 64 + i * 16 + quad * 4;
            #pragma unroll
            for (int r = 0; r < 4; r++)
                Cout[(row + r) * N + col] = acc[i][j][r] + bj;
        }
    }
}

// ---------------------------------------------------------------------------
// Flash attention via S^T = K @ Q^T (operand swap): lane holds 4 contiguous t
// per q -> vectorized b64 P stores, O^T = V^T @ P^T. Fold-pair Q tiles,
// double-buffered K/V, single barrier per iter, l = per-lane scalar accum.
// ---------------------------------------------------------------------------
__global__ __launch_bounds__(256, 2) void attn_mfma(const __bf16* __restrict__ qkv,
                                                    const __bf16* __restrict__ vt,
                                                    const int* __restrict__ mask,
                                                    __bf16* __restrict__ att) {
    __shared__ __align__(16) __bf16 Qs[128 * 64];
    __shared__ __align__(16) __bf16 Ks[2][64 * 64];
    __shared__ __align__(16) __bf16 Vs[2][64 * 64];
    __shared__ __align__(16) __bf16 Ps[4][16 * 64];  // per wave [q=16][t=64], 8B-chunk swizzled

    const int p = blockIdx.x, h = blockIdx.y, b = blockIdx.z;
    const int qlo = p, qhi = 15 - p, nk = 16 - p;
    const int tid = threadIdx.x, lane = tid & 63, wave = tid >> 6;
    const int l15 = lane & 15, quad = lane >> 4;

    // stage Q (swizzled chunks, strip-interleaved rows)
    #pragma unroll
    for (int i = 0; i < 4; i++) {
        int c = i * 256 + tid;
        int rr = c >> 3, ch = c & 7;
        int w_ = rr >> 5, s_ = (rr >> 4) & 1, r16 = rr & 15;
        int grow = (s_ ? qhi : qlo) * 64 + w_ * 16 + r16;
        gload16(&qkv[((size_t)(b * Tt + grow)) * 3072 + h * 64 + ((ch ^ (rr & 7)) * 8)],
                &Qs[c * 8]);
    }
    // stage K/V for kt=0 into buf 0
    #pragma unroll
    for (int i = 0; i < 2; i++) {
        int c = i * 256 + tid;
        int rr = c >> 3, ch = c & 7, sw = ((ch ^ (rr & 7)) * 8);
        gload16(&qkv[((size_t)(b * Tt + rr)) * 3072 + 1024 + h * 64 + sw], &Ks[0][c * 8]);
        gload16(&vt[((size_t)((b * Hh + h) * 64 + rr)) * Tt + sw], &Vs[0][c * 8]);
    }

    f32x4 Oacc[2][4] = {};   // [strip][d-tile]  (O^T layout: reg=d, lane col=q)
    float lsum[2] = { 0.0f, 0.0f };

    for (int kt = 0; kt < nk; kt++) {
        __syncthreads();
        const int cur = kt & 1;
        if (kt + 1 < nk) {  // prefetch next K/V (in flight across this iter)
            #pragma unroll
            for (int i = 0; i < 2; i++) {
                int c = i * 256 + tid;
                int rr = c >> 3, ch = c & 7, sw = ((ch ^ (rr & 7)) * 8);
                gload16(&qkv[((size_t)(b * Tt + (kt + 1) * 64 + rr)) * 3072 + 1024 + h * 64 + sw],
                        &Ks[cur ^ 1][c * 8]);
                gload16(&vt[((size_t)((b * Hh + h) * 64 + rr)) * Tt + (kt + 1) * 64 + sw],
                        &Vs[cur ^ 1][c * 8]);
            }
        }

        // mask: int4 per t-subrange (quad-uniform, L1 broadcast)
        int mv4[4][4];
        #pragma unroll
        for (int j = 0; j < 4; j++) {
            const int4 m4 = *(const int4*)&mask[b * Tt + kt * 64 + j * 16 + quad * 4];
            mv4[j][0] = m4.x; mv4[j][1] = m4.y; mv4[j][2] = m4.z; mv4[j][3] = m4.w;
        }

        // K/V A-fragments (shared by both strips)
        bf16x8 ak[4][2], av[4][2];
        #pragma unroll
        for (int j = 0; j < 4; j++)
            #pragma unroll
            for (int kc = 0; kc < 2; kc++) {
                int sw = (((kc * 4 + quad) ^ (l15 & 7)) * 8);
                ak[j][kc] = *(const bf16x8*)&Ks[cur][(j * 16 + l15) * 64 + sw];
                av[j][kc] = *(const bf16x8*)&Vs[cur][(j * 16 + l15) * 64 + sw];
            }

        #pragma unroll
        for (int s = 1; s >= 0; s--) {
            if (s == 0 && kt > qlo) continue;  // wave-uniform skip
            const int tile = s ? qhi : qlo;
            const int rowbase = wave * 32 + s * 16;
            // Q B-fragments (col = q = l15)
            bf16x8 q0 = *(const bf16x8*)&Qs[(rowbase + l15) * 64 + ((quad ^ (l15 & 7)) * 8)];
            bf16x8 q1 = *(const bf16x8*)&Qs[(rowbase + l15) * 64 + (((4 + quad) ^ (l15 & 7)) * 8)];

            #pragma unroll
            for (int j = 0; j < 4; j++) {
                f32x4 st = {};
                st = __builtin_amdgcn_mfma_f32_16x16x32_bf16(ak[j][0], q0, st, 0, 0, 0);
                st = __builtin_amdgcn_mfma_f32_16x16x32_bf16(ak[j][1], q1, st, 0, 0, 0);
                // lane holds S^T[t = j*16+quad*4+r][q = l15]
                bf16x4 pv;
                #pragma unroll
                for (int r = 0; r < 4; r++) {
                    const int tloc = j * 16 + quad * 4 + r;
                    bool keep = (mv4[j][r] != 0);
                    if (kt == tile) keep = keep && (tloc <= wave * 16 + l15);
                    const float pe = keep ? __expf(st[r]) : 0.0f;
                    lsum[s] += pe;
                    pv[r] = (__bf16)pe;
                }
                // b64 store: row q=l15, chunk c8=j*4+quad, swizzle bits1-3 by l15&7
                *(bf16x4*)&Ps[wave][l15 * 64 + (((j * 4 + quad) ^ ((l15 & 7) << 1)) * 4)] = pv;
            }
            // P^T B-frags: row l15, t-chunk pair 2*(kc*4+quad) (pair-preserving swizzle)
            bf16x8 p0 = *(const bf16x8*)&Ps[wave][l15 * 64 + (((2 * quad) ^ ((l15 & 7) << 1)) * 4)];
            bf16x8 p1 = *(const bf16x8*)&Ps[wave][l15 * 64 + (((2 * (4 + quad)) ^ ((l15 & 7) << 1)) * 4)];
            #pragma unroll
            for (int n = 0; n < 4; n++) {
                Oacc[s][n] = __builtin_amdgcn_mfma_f32_16x16x32_bf16(av[n][0], p0, Oacc[s][n], 0, 0, 0);
                Oacc[s][n] = __builtin_amdgcn_mfma_f32_16x16x32_bf16(av[n][1], p1, Oacc[s][n], 0, 0, 0);
            }
        }
    }

    // epilogue: reduce l across quads, normalize, store (O^T: lane col = q)
    #pragma unroll
    for (int s = 0; s < 2; s++) {
        const int tile = s ? qhi : qlo;
        float lt = lsum[s];
        lt += __shfl_xor(lt, 16);
        lt += __shfl_xor(lt, 32);
        const float inv = 1.0f / lt;
        const int q = tile * 64 + wave * 16 + l15;
        #pragma unroll
        for (int n = 0; n < 4; n++) {
            bf16x4 o;
            #pragma unroll
            for (int r = 0; r < 4; r++) o[r] = (__bf16)(Oacc[s][n][r] * inv);
            *(bf16x4*)&att[((size_t)(b * Tt + q)) * Dd + h * 64 + n * 16 + quad * 4] = o;
        }
    }
}

// ---------------------------------------------------------------------------
extern "C" void kernel_launch(void* const* d_in, const int* in_sizes, int n_in,
                              void* d_out, int out_size, void* d_ws, size_t ws_size,
                              hipStream_t stream) {
    const float* x     = (const float*)d_in[0];
    const float* Wqkv  = (const float*)d_in[1];
    const float* bqkv  = (const float*)d_in[2];
    const float* Wproj = (const float*)d_in[3];
    const float* bproj = (const float*)d_in[4];
    const int*   mask  = (const int*)d_in[5];
    float* out = (float*)d_out;

    __bf16* xb  = (__bf16*)d_ws;                         // 4096*1024
    __bf16* wqT = xb  + (size_t)4096 * 1024;             // 3072*1024
    __bf16* wpT = wqT + (size_t)3072 * 1024;             // 1024*1024
    __bf16* qkv = wpT + (size_t)1024 * 1024;             // 4096*3072
    __bf16* vt  = qkv + (size_t)4096 * 3072;             // 4*16*64*1024
    __bf16* att = vt  + (size_t)4 * 16 * 64 * 1024;      // 4096*1024

    cast_f32_bf16<<<4096, 256, 0, stream>>>(x, xb, (4096 * 1024) / 4);
    transpose_cast<<<dim3(16, 48), 256, 0, stream>>>(Wqkv, wqT, 1024, 3072);
    transpose_cast<<<dim3(16, 16), 256, 0, stream>>>(Wproj, wpT, 1024, 1024);

    // qkv = x @ Wqkv + b (Q cols pre-scaled by 0.125)
    gemm_bf16<<<dim3(24, 32), 256, 0, stream>>>(xb, wqT, bqkv, qkv, 4096, 3072, 1024, 1);

    v_transpose<<<dim3(16, 16, 4), 256, 0, stream>>>(qkv, vt);
    attn_mfma<<<dim3(8, 16, 4), 256, 0, stream>>>(qkv, vt, mask, att);

    gemm_bf16_n64<<<dim3(16, 32), 256, 0, stream>>>(att, wpT, bproj, out, 4096, 1024, 1024);
}